// Round 10
// baseline (130.672 us; speedup 1.0000x reference)
//
#include <hip/hip_runtime.h>
#include <cstdint>
#include <cstddef>

// SpikingHybridCoreFlow: 20-cycle spiking simulation.
// Exactness strategy (unchanged): fixed-point weights (4 x i8 planes, scale
// 2^-33), i8 MFMA integer GEMM (order-independent exact), fp64 membrane.
//
// R10: R9 dataflow (A-only 2x10KB LDS staging via global_load_lds; B operand
// in named double-buffered registers) + counted-vmcnt barriers: per kstep
//   STAGE_A(ks+1); LOADB(ks+1); COMPUTE(ks); s_waitcnt vmcnt(4); s_barrier;
// vmcnt(4) drains only the A-DMA (cross-wave visibility); the 4 B register
// loads stay in flight across the barrier -- compiler's own register
// dependency waits cover their use next iter. Never drain to 0 in the loop.
// R7's confound (3rd buffer -> 55KB block) and R8's confound
// (__launch_bounds__ 256,4 -> VGPR 64) are both removed: block stays 40,960B,
// launch_bounds stays (256,2).

#define N_DIM 2048
#define B_DIM 64
#define C_DIM 4
#define T_SIM 16
#define CYCLES 20
#define M_ROWS (CYCLES * B_DIM)          // 1280

using i32x4 = __attribute__((ext_vector_type(4))) int;
using u32x4 = __attribute__((ext_vector_type(4))) uint32_t;

// Workspace layout
//   WQ  : [C][128 strips][32 ksteps][4 planes][1024B] = 67,108,864 B
//   SIG : 4 x packed A matrices [80 mt][32 ks][1024B]  = 10,485,760 B
static constexpr size_t WQ_CORE    = (size_t)128 * 32 * 4 * 1024;   // 16 MB
static constexpr size_t SIG_OFF    = (size_t)C_DIM * WQ_CORE;
static constexpr size_t AMAT_BYTES = (size_t)M_ROWS * N_DIM;

#define WAITVM(n) asm volatile("s_waitcnt vmcnt(" #n ")" ::: "memory")

// Packed-A byte offset for logical (m, k); m = b*20 + t.
//   block = (m>>4)*32 + (k>>6); in-block = ((k>>4)&3)*256 + (m&15)*16 + (k&15)
// = the i8 16x16x64 A-fragment order (lane*16 + j).
__device__ __forceinline__ size_t apk_off(int m, int k) {
    return ((size_t)((m >> 4) * 32 + (k >> 6)) << 10)
         + (size_t)((((k >> 4) & 3) << 8) + ((m & 15) << 4) + (k & 15));
}

// ---------------------------------------------------------------------------
// Pack one (ct,ks) block of one core's W: fp32 -> i32 fixed point (scale 2^33)
// -> 4 balanced i8 planes, MFMA B-fragment order, coalesced dwordx4 stores.
// ---------------------------------------------------------------------------
__device__ __forceinline__ void pack_unit(const float* __restrict__ wc,
                                          signed char* __restrict__ wqc,
                                          int unit, int l) {
    int ct = unit & 127;
    int ks = unit >> 7;                // 0..31
    int n     = ct * 16 + (l & 15);
    int abase = ks * 64 + ((l >> 4) << 4);
    size_t blk_base = (((size_t)ct * 32 + ks) * 4) * 1024 + (size_t)l * 16;

    u32x4 d0, d1, d2, d3;
    for (int j4 = 0; j4 < 4; ++j4) {
        uint32_t w0 = 0, w1 = 0, w2 = 0, w3 = 0;
        for (int i = 0; i < 4; ++i) {
            int a = abase + j4 * 4 + i;
            float wv = wc[(size_t)a * N_DIM + n];
            long long vi = llrintf(wv * 8589934592.0f);        // * 2^33, exact
            int v  = (int)vi;
            int b0 = (int)(signed char)(v & 255); v = (v - b0) >> 8;
            int b1 = (int)(signed char)(v & 255); v = (v - b1) >> 8;
            int b2 = (int)(signed char)(v & 255); v = (v - b2) >> 8;
            int b3 = v;
            w0 |= (uint32_t)(uint8_t)b0 << (8 * i);
            w1 |= (uint32_t)(uint8_t)b1 << (8 * i);
            w2 |= (uint32_t)(uint8_t)b2 << (8 * i);
            w3 |= (uint32_t)(uint8_t)b3 << (8 * i);
        }
        d0[j4] = w0; d1[j4] = w1; d2[j4] = w2; d3[j4] = w3;
    }
    *(u32x4*)(wqc + blk_base)        = d0;
    *(u32x4*)(wqc + blk_base + 1024) = d1;
    *(u32x4*)(wqc + blk_base + 2048) = d2;
    *(u32x4*)(wqc + blk_base + 3072) = d3;
}

// ---------------------------------------------------------------------------
// Bit-exact replication of _uniform_spikes (IEEE fp32, like XLA).
// ---------------------------------------------------------------------------
__device__ __forceinline__ int in_spike(float xv, int cycle) {
    if (cycle >= T_SIM) return 0;
    float n_spk = rintf(xv * 16.0f);
    if (n_spk == 16.0f) return 1;
    if (n_spk == 0.0f)  return 0;
    float spacing = 16.0f / n_spk;
    float cf = (float)cycle;
    float q = floorf(cf / spacing);
    float r = fmodf(cf, spacing);
    return (q < n_spk && floorf(r) == 0.0f) ? 1 : 0;
}

// Packed core-0 A element group: row m = b*20 + t, 4 n's per thread.
__device__ __forceinline__ void gen_unit(const float* __restrict__ x,
                                         signed char* __restrict__ a0, int gid) {
    int e   = gid << 2;                            // logical m*2048 + n byte idx
    int row = e >> 11;                             // m = b*20 + t
    int b = row / 20, t = row - b * 20;
    int n0 = e & 2047;
    const float4 xv = *(const float4*)(x + (size_t)b * N_DIM + n0);
    uint32_t s = (uint32_t)in_spike(xv.x, t)
               | ((uint32_t)in_spike(xv.y, t) << 8)
               | ((uint32_t)in_spike(xv.z, t) << 16)
               | ((uint32_t)in_spike(xv.w, t) << 24);
    *(uint32_t*)(a0 + apk_off(row, n0)) = s;
}

// prep0: blocks [0,1024) pack core-0 W (4 units each); [1024,3584) gen input.
__global__ __launch_bounds__(256) void prep0(const float* __restrict__ w,
                                             signed char* __restrict__ wq,
                                             const float* __restrict__ x,
                                             signed char* __restrict__ a0) {
    int wg = blockIdx.x, tid = threadIdx.x;
    if (wg < 1024) {
        pack_unit(w, wq, (wg << 2) | (tid >> 6), tid & 63);
    } else {
        gen_unit(x, a0, (wg - 1024) * 256 + tid);
    }
}

// ---------------------------------------------------------------------------
// Fused batched-GEMM + threshold-scan for one core, + overlapped W_{c+1} pack.
// Gemm WGs (wg<512): 8 m-eighths (8 b's = 160 rows = 10 m-tiles) x 64 strips
// (32 cols). 256 thr = 4 waves; wave wv: nc = wv&1, m-tiles (wv>>1)*5+0..4.
// K-loop, unrolled x2 with named B double-buffers (bbA/bbB), counted vmcnt.
// Epilogue: exact plane combine -> fp64 scr[160][32] -> per-(b,n) scan.
// Pack WGs (wg>=512, c<3): pack W_{c+1} (memory-bound, overlaps gemm).
// ---------------------------------------------------------------------------
__global__ __launch_bounds__(256, 2) void gemm_core(
        signed char* __restrict__ wq, const signed char* __restrict__ apk,
        const float* __restrict__ wts, const float* __restrict__ biases,
        const float* __restrict__ thresholds,
        signed char* __restrict__ a_next, float* __restrict__ out, int c)
{
    __shared__ __align__(16) signed char smem[40960];   // 2x10KB stage | scr
    const int wg  = blockIdx.x;
    const int tid = threadIdx.x;
    const int wv  = tid >> 6;          // 0..3
    const int l   = tid & 63;

    if (wg >= 512) {                   // overlapped pack of W_{c+1}
        pack_unit(wts + (size_t)(c + 1) * N_DIM * N_DIM,
                  wq + (size_t)(c + 1) * WQ_CORE,
                  ((wg - 512) << 2) | wv, l);
        return;
    }

    const int e8 = wg >> 6;            // m-eighth: b in [8*e8, 8*e8+8)
    const int s  = wg & 63;            // 32-col strip: n in [32s, 32s+32)
    const int nc  = wv & 1;            // n-fragment (16 cols)
    const int mtb = (wv >> 1) * 5;     // first of 5 m-tiles

    const signed char* asrc = apk + ((size_t)(e8 * 10) * 32) * 1024;
    const signed char* bsrc = wq + ((size_t)(c * 128 + s * 2 + nc) * 32) * 4096
                            + (size_t)l * 16;

    // Stage A slice ks into buffer buf: 10 blocks of 1KB, waves take 3/3/3/1.
    auto STAGE = [&](int buf, int ks) {
        signed char* dst = smem + buf * 10240;
#pragma unroll
        for (int r = 0; r < 3; ++r) {
            int blk = wv * 3 + r;
            if (blk < 10) {
                __builtin_amdgcn_global_load_lds(
                    (const __attribute__((address_space(1))) uint32_t*)
                        (asrc + ((size_t)blk * 32 + ks) * 1024 + l * 16),
                    (__attribute__((address_space(3))) uint32_t*)(dst + blk * 1024),
                    16, 0, 0);
            }
        }
    };

    auto LOADB = [&](i32x4* bb, int ks) {
        const signed char* bk = bsrc + (size_t)ks * 4096;
#pragma unroll
        for (int p = 0; p < 4; ++p)
            bb[p] = *(const i32x4*)(bk + p * 1024);
    };

    auto COMPUTE = [&](i32x4 (*acc)[4], int buf, const i32x4* bb) {
        const signed char* lb = smem + buf * 10240 + (size_t)l * 16;
#pragma unroll
        for (int j = 0; j < 5; ++j) {
            i32x4 af = *(const i32x4*)(lb + (mtb + j) * 1024);
            acc[j][0] = __builtin_amdgcn_mfma_i32_16x16x64_i8(af, bb[0], acc[j][0], 0, 0, 0);
            acc[j][1] = __builtin_amdgcn_mfma_i32_16x16x64_i8(af, bb[1], acc[j][1], 0, 0, 0);
            acc[j][2] = __builtin_amdgcn_mfma_i32_16x16x64_i8(af, bb[2], acc[j][2], 0, 0, 0);
            acc[j][3] = __builtin_amdgcn_mfma_i32_16x16x64_i8(af, bb[3], acc[j][3], 0, 0, 0);
        }
    };

    i32x4 acc[5][4];
#pragma unroll
    for (int j = 0; j < 5; ++j)
#pragma unroll
        for (int p = 0; p < 4; ++p) acc[j][p] = i32x4{0, 0, 0, 0};

    i32x4 bbA[4], bbB[4];
    // Prologue: stage A(0), load B(0); drain A-DMA only (B flies) -> barrier.
    STAGE(0, 0);
    LOADB(bbA, 0);
    WAITVM(4);
    __builtin_amdgcn_s_barrier();
    int cur = 0;

#pragma unroll 1
    for (int k2 = 0; k2 < 16; ++k2) {
        const int ks = k2 * 2;
        // even step: prefetch ks+1 (A->LDS, B->bbB); compute slice ks (bbA).
        STAGE(cur ^ 1, ks + 1);
        LOADB(bbB, ks + 1);
        COMPUTE(acc, cur, bbA);
        WAITVM(4);                     // my A-DMA(ks+1) landed; B(ks+1) flies
        __builtin_amdgcn_s_barrier();  // all waves' A(ks+1) visible, reads done
        cur ^= 1;
        // odd step: prefetch ks+2; compute slice ks+1 (bbB).
        if (k2 < 15) {
            STAGE(cur ^ 1, ks + 2);
            LOADB(bbA, ks + 2);
            COMPUTE(acc, cur, bbB);
            WAITVM(4);
        } else {
            COMPUTE(acc, cur, bbB);
            WAITVM(0);
        }
        __builtin_amdgcn_s_barrier();
        cur ^= 1;
    }
    __syncthreads();                   // full drain before scr overlay

    // ---- Fused epilogue ----
    // 1. Combine planes exactly -> fp64 increments into LDS (staging is dead).
    double* scr = (double*)smem;       // [160][32]
    const int nl = nc * 16 + (l & 15);
#pragma unroll
    for (int j = 0; j < 5; ++j) {
#pragma unroll
        for (int r = 0; r < 4; ++r) {
            int rl = (mtb + j) * 16 + ((l >> 4) << 2) + r;   // local row 0..159
            long long comb = ((long long)acc[j][3][r] << 24) + ((long long)acc[j][2][r] << 16)
                           + ((long long)acc[j][1][r] << 8)  +  (long long)acc[j][0][r];
            scr[rl * 32 + nl] = (double)comb * (1.0 / 8589934592.0);
        }
    }
    __syncthreads();

    // 2. Per-(b,n) threshold scan over t=0..19; thread <-> (b_loc, n_loc).
    const int b_loc = tid >> 5;        // 0..7
    const int n_loc = tid & 31;        // 0..31
    const int b = e8 * 8 + b_loc;
    const int n = (s << 5) + n_loc;
    const double bv = (double)biases[c * N_DIM + n];
    const double th = (double)thresholds[c];
    double m = 0.0;
    float cnt = 0.0f;
    if (c < 3) a_next[apk_off(b * 20, n)] = 0;     // zero input at t=0
    for (int t = 0; t < CYCLES; ++t) {
        m = m + scr[(b_loc * 20 + t) * 32 + n_loc] + bv;
        bool sp = (th < m);
        if (sp) m -= th;
        if (c < 3) {
            if (t + 1 < CYCLES) a_next[apk_off(b * 20 + t + 1, n)] = sp ? 1 : 0;
        } else if (sp) {
            cnt += 1.0f;
        }
    }
    if (c == 3) out[(size_t)b * N_DIM + n] = cnt * 0.0625f;  // /16, exact
}

extern "C" void kernel_launch(void* const* d_in, const int* in_sizes, int n_in,
                              void* d_out, int out_size, void* d_ws, size_t ws_size,
                              hipStream_t stream) {
    const float* x       = (const float*)d_in[0];
    const float* wts     = (const float*)d_in[1];
    const float* biases  = (const float*)d_in[2];
    const float* thr     = (const float*)d_in[3];
    float* out           = (float*)d_out;

    signed char* wq  = (signed char*)d_ws;
    signed char* sig = (signed char*)((char*)d_ws + SIG_OFF);

    // prep0: pack W0 + build packed core-0 input spikes (no memsets needed:
    // every consumed byte is written by a producer before its consumer runs).
    prep0<<<dim3(3584), dim3(256), 0, stream>>>(wts, wq, x, sig);

    // 4 pipeline stages: fused GEMM+scan, with W_{c+1} pack overlapped.
    for (int c = 0; c < C_DIM; ++c) {
        const signed char* a_cur = sig + (size_t)c * AMAT_BYTES;
        signed char* a_nxt = (c < 3) ? (signed char*)(sig + (size_t)(c + 1) * AMAT_BYTES)
                                     : (signed char*)sig;   // unused for c==3
        int grid = (c < 3) ? 1536 : 512;
        gemm_core<<<dim3(grid), dim3(256), 0, stream>>>(wq, a_cur, wts, biases,
                                                        thr, a_nxt, out, c);
    }
}

// Round 11
// 120.439 us; speedup vs baseline: 1.0850x; 1.0850x over previous
//
#include <hip/hip_runtime.h>
#include <cstdint>
#include <cstddef>

// SpikingHybridCoreFlow: 20-cycle spiking simulation.
// Exactness strategy (unchanged): fixed-point weights (4 x i8 planes, scale
// 2^-33), i8 MFMA integer GEMM (order-independent exact), fp64 membrane.
//
// R11: ZERO-SYNC streaming k-loop. R6 diagnosis: LDS pipe (36 ds_read_b128 +
// 18KB DMA writes per WG-kstep) exceeds the MFMA pipe, plus a vmcnt(0)
// barrier drain every kstep; R7/R8/R10 hand-scheduling attempts all
// regressed. So: remove LDS and barriers from the loop entirely. A and B
// fragments load straight to VGPRs (plain compiler-tracked loads, 1KB
// contiguous per wave-fragment, L2/L1-resident), named double-buffered
// operand sets (static indexing), no barriers until the epilogue. Latency
// hiding = TLP + compiler pipelining. LDS holds only the epilogue scan
// scratch (40,960B -> occupancy unchanged).

#define N_DIM 2048
#define B_DIM 64
#define C_DIM 4
#define T_SIM 16
#define CYCLES 20
#define M_ROWS (CYCLES * B_DIM)          // 1280

using i32x4 = __attribute__((ext_vector_type(4))) int;
using u32x4 = __attribute__((ext_vector_type(4))) uint32_t;

// Workspace layout
//   WQ  : [C][128 strips][32 ksteps][4 planes][1024B] = 67,108,864 B
//   SIG : 4 x packed A matrices [80 mt][32 ks][1024B]  = 10,485,760 B
static constexpr size_t WQ_CORE    = (size_t)128 * 32 * 4 * 1024;   // 16 MB
static constexpr size_t SIG_OFF    = (size_t)C_DIM * WQ_CORE;
static constexpr size_t AMAT_BYTES = (size_t)M_ROWS * N_DIM;

// Packed-A byte offset for logical (m, k); m = b*20 + t.
//   block = (m>>4)*32 + (k>>6); in-block = ((k>>4)&3)*256 + (m&15)*16 + (k&15)
// = the i8 16x16x64 A-fragment order (lane*16 + j).
__device__ __forceinline__ size_t apk_off(int m, int k) {
    return ((size_t)((m >> 4) * 32 + (k >> 6)) << 10)
         + (size_t)((((k >> 4) & 3) << 8) + ((m & 15) << 4) + (k & 15));
}

// ---------------------------------------------------------------------------
// Pack one (ct,ks) block of one core's W: fp32 -> i32 fixed point (scale 2^33)
// -> 4 balanced i8 planes, MFMA B-fragment order, coalesced dwordx4 stores.
// ---------------------------------------------------------------------------
__device__ __forceinline__ void pack_unit(const float* __restrict__ wc,
                                          signed char* __restrict__ wqc,
                                          int unit, int l) {
    int ct = unit & 127;
    int ks = unit >> 7;                // 0..31
    int n     = ct * 16 + (l & 15);
    int abase = ks * 64 + ((l >> 4) << 4);
    size_t blk_base = (((size_t)ct * 32 + ks) * 4) * 1024 + (size_t)l * 16;

    u32x4 d0, d1, d2, d3;
    for (int j4 = 0; j4 < 4; ++j4) {
        uint32_t w0 = 0, w1 = 0, w2 = 0, w3 = 0;
        for (int i = 0; i < 4; ++i) {
            int a = abase + j4 * 4 + i;
            float wv = wc[(size_t)a * N_DIM + n];
            long long vi = llrintf(wv * 8589934592.0f);        // * 2^33, exact
            int v  = (int)vi;
            int b0 = (int)(signed char)(v & 255); v = (v - b0) >> 8;
            int b1 = (int)(signed char)(v & 255); v = (v - b1) >> 8;
            int b2 = (int)(signed char)(v & 255); v = (v - b2) >> 8;
            int b3 = v;
            w0 |= (uint32_t)(uint8_t)b0 << (8 * i);
            w1 |= (uint32_t)(uint8_t)b1 << (8 * i);
            w2 |= (uint32_t)(uint8_t)b2 << (8 * i);
            w3 |= (uint32_t)(uint8_t)b3 << (8 * i);
        }
        d0[j4] = w0; d1[j4] = w1; d2[j4] = w2; d3[j4] = w3;
    }
    *(u32x4*)(wqc + blk_base)        = d0;
    *(u32x4*)(wqc + blk_base + 1024) = d1;
    *(u32x4*)(wqc + blk_base + 2048) = d2;
    *(u32x4*)(wqc + blk_base + 3072) = d3;
}

// ---------------------------------------------------------------------------
// Bit-exact replication of _uniform_spikes (IEEE fp32, like XLA).
// ---------------------------------------------------------------------------
__device__ __forceinline__ int in_spike(float xv, int cycle) {
    if (cycle >= T_SIM) return 0;
    float n_spk = rintf(xv * 16.0f);
    if (n_spk == 16.0f) return 1;
    if (n_spk == 0.0f)  return 0;
    float spacing = 16.0f / n_spk;
    float cf = (float)cycle;
    float q = floorf(cf / spacing);
    float r = fmodf(cf, spacing);
    return (q < n_spk && floorf(r) == 0.0f) ? 1 : 0;
}

// Packed core-0 A element group: row m = b*20 + t, 4 n's per thread.
__device__ __forceinline__ void gen_unit(const float* __restrict__ x,
                                         signed char* __restrict__ a0, int gid) {
    int e   = gid << 2;                            // logical m*2048 + n byte idx
    int row = e >> 11;                             // m = b*20 + t
    int b = row / 20, t = row - b * 20;
    int n0 = e & 2047;
    const float4 xv = *(const float4*)(x + (size_t)b * N_DIM + n0);
    uint32_t s = (uint32_t)in_spike(xv.x, t)
               | ((uint32_t)in_spike(xv.y, t) << 8)
               | ((uint32_t)in_spike(xv.z, t) << 16)
               | ((uint32_t)in_spike(xv.w, t) << 24);
    *(uint32_t*)(a0 + apk_off(row, n0)) = s;
}

// prep0: blocks [0,1024) pack core-0 W (4 units each); [1024,3584) gen input.
__global__ __launch_bounds__(256) void prep0(const float* __restrict__ w,
                                             signed char* __restrict__ wq,
                                             const float* __restrict__ x,
                                             signed char* __restrict__ a0) {
    int wg = blockIdx.x, tid = threadIdx.x;
    if (wg < 1024) {
        pack_unit(w, wq, (wg << 2) | (tid >> 6), tid & 63);
    } else {
        gen_unit(x, a0, (wg - 1024) * 256 + tid);
    }
}

// ---------------------------------------------------------------------------
// Fused batched-GEMM + threshold-scan for one core, + overlapped W_{c+1} pack.
// Gemm WGs (wg<512): 8 m-eighths (8 b's = 160 rows = 10 m-tiles) x 64 strips
// (32 cols). 256 thr = 4 waves; wave wv: nc = wv&1, m-tiles (wv>>1)*5+0..4.
// K-loop: no LDS, no barriers. Per slice: 5 A-frag + 4 B-frag register loads
// (each 1KB contiguous per wave, L2/L1-hot) + 20 MFMAs; named double-buffered
// sets, unroll x2. Compiler inserts counted waits; TLP hides latency.
// Epilogue: exact plane combine -> fp64 scr[160][32] (LDS) -> per-(b,n) scan.
// Pack WGs (wg>=512, c<3): pack W_{c+1} (memory-bound, overlaps gemm).
// ---------------------------------------------------------------------------
__global__ __launch_bounds__(256, 2) void gemm_core(
        signed char* __restrict__ wq, const signed char* __restrict__ apk,
        const float* __restrict__ wts, const float* __restrict__ biases,
        const float* __restrict__ thresholds,
        signed char* __restrict__ a_next, float* __restrict__ out, int c)
{
    __shared__ __align__(16) double scr[160][32];       // 40,960 B (epilogue)
    const int wg  = blockIdx.x;
    const int tid = threadIdx.x;
    const int wv  = tid >> 6;          // 0..3
    const int l   = tid & 63;

    if (wg >= 512) {                   // overlapped pack of W_{c+1}
        pack_unit(wts + (size_t)(c + 1) * N_DIM * N_DIM,
                  wq + (size_t)(c + 1) * WQ_CORE,
                  ((wg - 512) << 2) | wv, l);
        return;
    }

    const int e8 = wg >> 6;            // m-eighth: b in [8*e8, 8*e8+8)
    const int s  = wg & 63;            // 32-col strip: n in [32s, 32s+32)
    const int nc  = wv & 1;            // n-fragment (16 cols)
    const int mtb = (wv >> 1) * 5;     // first of 5 m-tiles

    // Per-wave source pointers (lane offset folded in).
    const signed char* asrc = apk + ((size_t)(e8 * 10 + mtb) * 32) * 1024
                            + (size_t)l * 16;
    const signed char* bsrc = wq + ((size_t)(c * 128 + s * 2 + nc) * 32) * 4096
                            + (size_t)l * 16;

    auto LOADA = [&](i32x4* aa, int ks) {
#pragma unroll
        for (int j = 0; j < 5; ++j)
            aa[j] = *(const i32x4*)(asrc + ((size_t)j * 32 + ks) * 1024);
    };
    auto LOADB = [&](i32x4* bb, int ks) {
        const signed char* bk = bsrc + (size_t)ks * 4096;
#pragma unroll
        for (int p = 0; p < 4; ++p)
            bb[p] = *(const i32x4*)(bk + p * 1024);
    };
    auto COMPUTE = [&](i32x4 (*acc)[4], const i32x4* aa, const i32x4* bb) {
#pragma unroll
        for (int j = 0; j < 5; ++j) {
            acc[j][0] = __builtin_amdgcn_mfma_i32_16x16x64_i8(aa[j], bb[0], acc[j][0], 0, 0, 0);
            acc[j][1] = __builtin_amdgcn_mfma_i32_16x16x64_i8(aa[j], bb[1], acc[j][1], 0, 0, 0);
            acc[j][2] = __builtin_amdgcn_mfma_i32_16x16x64_i8(aa[j], bb[2], acc[j][2], 0, 0, 0);
            acc[j][3] = __builtin_amdgcn_mfma_i32_16x16x64_i8(aa[j], bb[3], acc[j][3], 0, 0, 0);
        }
    };

    i32x4 acc[5][4];
#pragma unroll
    for (int j = 0; j < 5; ++j)
#pragma unroll
        for (int p = 0; p < 4; ++p) acc[j][p] = i32x4{0, 0, 0, 0};

    i32x4 aA[5], bA[4], aB[5], bB[4];
    LOADA(aA, 0); LOADB(bA, 0);

#pragma unroll 1
    for (int k2 = 0; k2 < 16; ++k2) {
        const int ks = k2 * 2;
        LOADA(aB, ks + 1); LOADB(bB, ks + 1);      // prefetch odd slice
        COMPUTE(acc, aA, bA);                      // compute even slice
        if (k2 < 15) { LOADA(aA, ks + 2); LOADB(bA, ks + 2); }  // prefetch even
        COMPUTE(acc, aB, bB);                      // compute odd slice
    }

    // ---- Fused epilogue ----
    // 1. Combine planes exactly -> fp64 increments into LDS.
    const int nl = nc * 16 + (l & 15);
#pragma unroll
    for (int j = 0; j < 5; ++j) {
#pragma unroll
        for (int r = 0; r < 4; ++r) {
            int rl = (mtb + j) * 16 + ((l >> 4) << 2) + r;   // local row 0..159
            long long comb = ((long long)acc[j][3][r] << 24) + ((long long)acc[j][2][r] << 16)
                           + ((long long)acc[j][1][r] << 8)  +  (long long)acc[j][0][r];
            scr[rl][nl] = (double)comb * (1.0 / 8589934592.0);
        }
    }
    __syncthreads();

    // 2. Per-(b,n) threshold scan over t=0..19; thread <-> (b_loc, n_loc).
    const int b_loc = tid >> 5;        // 0..7
    const int n_loc = tid & 31;        // 0..31
    const int b = e8 * 8 + b_loc;
    const int n = (s << 5) + n_loc;
    const double bv = (double)biases[c * N_DIM + n];
    const double th = (double)thresholds[c];
    double m = 0.0;
    float cnt = 0.0f;
    if (c < 3) a_next[apk_off(b * 20, n)] = 0;     // zero input at t=0
    for (int t = 0; t < CYCLES; ++t) {
        m = m + scr[b_loc * 20 + t][n_loc] + bv;
        bool sp = (th < m);
        if (sp) m -= th;
        if (c < 3) {
            if (t + 1 < CYCLES) a_next[apk_off(b * 20 + t + 1, n)] = sp ? 1 : 0;
        } else if (sp) {
            cnt += 1.0f;
        }
    }
    if (c == 3) out[(size_t)b * N_DIM + n] = cnt * 0.0625f;  // /16, exact
}

extern "C" void kernel_launch(void* const* d_in, const int* in_sizes, int n_in,
                              void* d_out, int out_size, void* d_ws, size_t ws_size,
                              hipStream_t stream) {
    const float* x       = (const float*)d_in[0];
    const float* wts     = (const float*)d_in[1];
    const float* biases  = (const float*)d_in[2];
    const float* thr     = (const float*)d_in[3];
    float* out           = (float*)d_out;

    signed char* wq  = (signed char*)d_ws;
    signed char* sig = (signed char*)((char*)d_ws + SIG_OFF);

    // prep0: pack W0 + build packed core-0 input spikes (no memsets needed:
    // every consumed byte is written by a producer before its consumer runs).
    prep0<<<dim3(3584), dim3(256), 0, stream>>>(wts, wq, x, sig);

    // 4 pipeline stages: fused GEMM+scan, with W_{c+1} pack overlapped.
    for (int c = 0; c < C_DIM; ++c) {
        const signed char* a_cur = sig + (size_t)c * AMAT_BYTES;
        signed char* a_nxt = (c < 3) ? (signed char*)(sig + (size_t)(c + 1) * AMAT_BYTES)
                                     : (signed char*)sig;   // unused for c==3
        int grid = (c < 3) ? 1536 : 512;
        gemm_core<<<dim3(grid), dim3(256), 0, stream>>>(wq, a_cur, wts, biases,
                                                        thr, a_nxt, out, c);
    }
}

// Round 12
// 112.778 us; speedup vs baseline: 1.1587x; 1.0679x over previous
//
#include <hip/hip_runtime.h>
#include <cstdint>
#include <cstddef>

// SpikingHybridCoreFlow: 20-cycle spiking simulation.
// Exactness strategy (unchanged): fixed-point weights (4 x i8 planes, scale
// 2^-33), i8 MFMA integer GEMM (order-independent exact), fp64 membrane.
//
// R12: R6 (best known) with ONE change: each LDS double-buffer now holds TWO
// k-steps (36,864B per buffer, per-kstep sub-layout identical to R6), so the
// k-loop runs 16 iterations with one __syncthreads each instead of 32 --
// halving the per-barrier vmcnt(0) drain tax identified as R6's residual
// overhead. Block LDS 73,728B keeps exactly 2 WGs/CU. No inline asm, no
// launch_bounds change, no VGPR pressure change (R7/R8/R10 failure modes
// all absent).

#define N_DIM 2048
#define B_DIM 64
#define C_DIM 4
#define T_SIM 16
#define CYCLES 20
#define M_ROWS (CYCLES * B_DIM)          // 1280

using i32x4 = __attribute__((ext_vector_type(4))) int;
using u32x4 = __attribute__((ext_vector_type(4))) uint32_t;

// Workspace layout
//   WQ  : [C][128 strips][32 ksteps][4 planes][1024B] = 67,108,864 B
//   SIG : 4 x packed A matrices [80 mt][32 ks][1024B]  = 10,485,760 B
static constexpr size_t WQ_CORE    = (size_t)128 * 32 * 4 * 1024;   // 16 MB
static constexpr size_t SIG_OFF    = (size_t)C_DIM * WQ_CORE;
static constexpr size_t AMAT_BYTES = (size_t)M_ROWS * N_DIM;

// Packed-A byte offset for logical (m, k); m = b*20 + t.
//   block = (m>>4)*32 + (k>>6); in-block = ((k>>4)&3)*256 + (m&15)*16 + (k&15)
// = the i8 16x16x64 A-fragment order (lane*16 + j).
__device__ __forceinline__ size_t apk_off(int m, int k) {
    return ((size_t)((m >> 4) * 32 + (k >> 6)) << 10)
         + (size_t)((((k >> 4) & 3) << 8) + ((m & 15) << 4) + (k & 15));
}

// ---------------------------------------------------------------------------
// Pack one (ct,ks) block of one core's W: fp32 -> i32 fixed point (scale 2^33)
// -> 4 balanced i8 planes, MFMA B-fragment order, coalesced dwordx4 stores.
// ---------------------------------------------------------------------------
__device__ __forceinline__ void pack_unit(const float* __restrict__ wc,
                                          signed char* __restrict__ wqc,
                                          int unit, int l) {
    int ct = unit & 127;
    int ks = unit >> 7;                // 0..31
    int n     = ct * 16 + (l & 15);
    int abase = ks * 64 + ((l >> 4) << 4);
    size_t blk_base = (((size_t)ct * 32 + ks) * 4) * 1024 + (size_t)l * 16;

    u32x4 d0, d1, d2, d3;
    for (int j4 = 0; j4 < 4; ++j4) {
        uint32_t w0 = 0, w1 = 0, w2 = 0, w3 = 0;
        for (int i = 0; i < 4; ++i) {
            int a = abase + j4 * 4 + i;
            float wv = wc[(size_t)a * N_DIM + n];
            long long vi = llrintf(wv * 8589934592.0f);        // * 2^33, exact
            int v  = (int)vi;
            int b0 = (int)(signed char)(v & 255); v = (v - b0) >> 8;
            int b1 = (int)(signed char)(v & 255); v = (v - b1) >> 8;
            int b2 = (int)(signed char)(v & 255); v = (v - b2) >> 8;
            int b3 = v;
            w0 |= (uint32_t)(uint8_t)b0 << (8 * i);
            w1 |= (uint32_t)(uint8_t)b1 << (8 * i);
            w2 |= (uint32_t)(uint8_t)b2 << (8 * i);
            w3 |= (uint32_t)(uint8_t)b3 << (8 * i);
        }
        d0[j4] = w0; d1[j4] = w1; d2[j4] = w2; d3[j4] = w3;
    }
    *(u32x4*)(wqc + blk_base)        = d0;
    *(u32x4*)(wqc + blk_base + 1024) = d1;
    *(u32x4*)(wqc + blk_base + 2048) = d2;
    *(u32x4*)(wqc + blk_base + 3072) = d3;
}

// ---------------------------------------------------------------------------
// Bit-exact replication of _uniform_spikes (IEEE fp32, like XLA).
// ---------------------------------------------------------------------------
__device__ __forceinline__ int in_spike(float xv, int cycle) {
    if (cycle >= T_SIM) return 0;
    float n_spk = rintf(xv * 16.0f);
    if (n_spk == 16.0f) return 1;
    if (n_spk == 0.0f)  return 0;
    float spacing = 16.0f / n_spk;
    float cf = (float)cycle;
    float q = floorf(cf / spacing);
    float r = fmodf(cf, spacing);
    return (q < n_spk && floorf(r) == 0.0f) ? 1 : 0;
}

// Packed core-0 A element group: row m = b*20 + t, 4 n's per thread.
__device__ __forceinline__ void gen_unit(const float* __restrict__ x,
                                         signed char* __restrict__ a0, int gid) {
    int e   = gid << 2;                            // logical m*2048 + n byte idx
    int row = e >> 11;                             // m = b*20 + t
    int b = row / 20, t = row - b * 20;
    int n0 = e & 2047;
    const float4 xv = *(const float4*)(x + (size_t)b * N_DIM + n0);
    uint32_t s = (uint32_t)in_spike(xv.x, t)
               | ((uint32_t)in_spike(xv.y, t) << 8)
               | ((uint32_t)in_spike(xv.z, t) << 16)
               | ((uint32_t)in_spike(xv.w, t) << 24);
    *(uint32_t*)(a0 + apk_off(row, n0)) = s;
}

// prep0: blocks [0,1024) pack core-0 W (4 units each); [1024,3584) gen input.
__global__ __launch_bounds__(256) void prep0(const float* __restrict__ w,
                                             signed char* __restrict__ wq,
                                             const float* __restrict__ x,
                                             signed char* __restrict__ a0) {
    int wg = blockIdx.x, tid = threadIdx.x;
    if (wg < 1024) {
        pack_unit(w, wq, (wg << 2) | (tid >> 6), tid & 63);
    } else {
        gen_unit(x, a0, (wg - 1024) * 256 + tid);
    }
}

// ---------------------------------------------------------------------------
// Fused batched-GEMM + threshold-scan for one core, + overlapped W_{c+1} pack.
// Gemm WGs (wg<512): 8 m-eighths (8 b's = 160 rows = 10 m-tiles) x 64 strips
// (32 cols). 256 thr = 4 waves; wave wv: nc = wv&1, m-tiles (wv>>1)*5+0..4.
// K-loop: 16 iterations; each LDS buffer holds 2 k-steps (per-kstep layout =
// R6: A 10KB @ 0, B 8KB @ 10240; second kstep at +18432). Per iter:
//   STAGE2(buf^1, pair t+1); compute sub0 (20 MFMA); compute sub1 (20 MFMA);
//   one __syncthreads.
// Epilogue: exact plane combine -> fp64 scr[160][33] -> per-(b,n) scan.
// Pack WGs (wg>=512, c<3): pack W_{c+1} (memory-bound, overlaps gemm).
// ---------------------------------------------------------------------------
__global__ __launch_bounds__(256, 2) void gemm_core(
        signed char* __restrict__ wq, const signed char* __restrict__ apk,
        const float* __restrict__ wts, const float* __restrict__ biases,
        const float* __restrict__ thresholds,
        signed char* __restrict__ a_next, float* __restrict__ out, int c)
{
    __shared__ __align__(16) signed char smem[73728];   // 2 x 36,864B buffers
    const int wg  = blockIdx.x;
    const int tid = threadIdx.x;
    const int wv  = tid >> 6;          // 0..3
    const int l   = tid & 63;

    if (wg >= 512) {                   // overlapped pack of W_{c+1}
        pack_unit(wts + (size_t)(c + 1) * N_DIM * N_DIM,
                  wq + (size_t)(c + 1) * WQ_CORE,
                  ((wg - 512) << 2) | wv, l);
        return;
    }

    const int e8 = wg >> 6;            // m-eighth: b in [8*e8, 8*e8+8)
    const int s  = wg & 63;            // 32-col strip: n in [32s, 32s+32)
    const int nc  = wv & 1;            // n-fragment (16 cols)
    const int mtb = (wv >> 1) * 5;     // first of 5 m-tiles

    const signed char* asrc  = apk + ((size_t)(e8 * 10) * 32) * 1024;
    const signed char* b0src = wq + ((size_t)(c * 128 + s * 2) * 32) * 4096;
    const signed char* b1src = wq + ((size_t)(c * 128 + s * 2 + 1) * 32) * 4096;

    // Stage k-step pair {2t, 2t+1} into buffer buf. Waves 0,1: A blocks
    // (5 each per sub-kstep); waves 2,3: B strip0/strip1 (4 plane-blocks).
    auto STAGE2 = [&](int buf, int t) {
        signed char* base = smem + buf * 36864;
#pragma unroll
        for (int sub = 0; sub < 2; ++sub) {
            const int ks = t * 2 + sub;
            signed char* dst = base + sub * 18432;
            if (wv < 2) {
#pragma unroll
                for (int r = 0; r < 5; ++r) {
                    int blk = wv * 5 + r;
                    __builtin_amdgcn_global_load_lds(
                        (const __attribute__((address_space(1))) uint32_t*)
                            (asrc + ((size_t)blk * 32 + ks) * 1024 + l * 16),
                        (__attribute__((address_space(3))) uint32_t*)(dst + blk * 1024),
                        16, 0, 0);
                }
            } else {
                const signed char* bs = (wv == 2) ? b0src : b1src;
#pragma unroll
                for (int p = 0; p < 4; ++p) {
                    __builtin_amdgcn_global_load_lds(
                        (const __attribute__((address_space(1))) uint32_t*)
                            (bs + (size_t)ks * 4096 + p * 1024 + l * 16),
                        (__attribute__((address_space(3))) uint32_t*)
                            (dst + 10240 + (wv - 2) * 4096 + p * 1024),
                        16, 0, 0);
                }
            }
        }
    };

    i32x4 acc[5][4];
#pragma unroll
    for (int j = 0; j < 5; ++j)
#pragma unroll
        for (int p = 0; p < 4; ++p) acc[j][p] = i32x4{0, 0, 0, 0};

    STAGE2(0, 0);
    __syncthreads();
    int cur = 0;

#pragma unroll 1
    for (int t = 0; t < 16; ++t) {
        if (t < 15) STAGE2(cur ^ 1, t + 1);
#pragma unroll
        for (int sub = 0; sub < 2; ++sub) {
            const signed char* lb = smem + cur * 36864 + sub * 18432
                                  + (size_t)l * 16;
            i32x4 bf0 = *(const i32x4*)(lb + 10240 + nc * 4096);
            i32x4 bf1 = *(const i32x4*)(lb + 10240 + nc * 4096 + 1024);
            i32x4 bf2 = *(const i32x4*)(lb + 10240 + nc * 4096 + 2048);
            i32x4 bf3 = *(const i32x4*)(lb + 10240 + nc * 4096 + 3072);
#pragma unroll
            for (int j = 0; j < 5; ++j) {
                i32x4 af = *(const i32x4*)(lb + (mtb + j) * 1024);
                acc[j][0] = __builtin_amdgcn_mfma_i32_16x16x64_i8(af, bf0, acc[j][0], 0, 0, 0);
                acc[j][1] = __builtin_amdgcn_mfma_i32_16x16x64_i8(af, bf1, acc[j][1], 0, 0, 0);
                acc[j][2] = __builtin_amdgcn_mfma_i32_16x16x64_i8(af, bf2, acc[j][2], 0, 0, 0);
                acc[j][3] = __builtin_amdgcn_mfma_i32_16x16x64_i8(af, bf3, acc[j][3], 0, 0, 0);
            }
        }
        __syncthreads();
        cur ^= 1;
    }

    // ---- Fused epilogue ----
    // 1. Combine planes exactly -> fp64 increments into LDS (staging is dead).
    double* scr = (double*)smem;       // [160][33]
    const int nl = nc * 16 + (l & 15);
#pragma unroll
    for (int j = 0; j < 5; ++j) {
#pragma unroll
        for (int r = 0; r < 4; ++r) {
            int rl = (mtb + j) * 16 + ((l >> 4) << 2) + r;   // local row 0..159
            long long comb = ((long long)acc[j][3][r] << 24) + ((long long)acc[j][2][r] << 16)
                           + ((long long)acc[j][1][r] << 8)  +  (long long)acc[j][0][r];
            scr[rl * 33 + nl] = (double)comb * (1.0 / 8589934592.0);
        }
    }
    __syncthreads();

    // 2. Per-(b,n) threshold scan over t=0..19; thread <-> (b_loc, n_loc).
    const int b_loc = tid >> 5;        // 0..7
    const int n_loc = tid & 31;        // 0..31
    const int b = e8 * 8 + b_loc;
    const int n = (s << 5) + n_loc;
    const double bv = (double)biases[c * N_DIM + n];
    const double th = (double)thresholds[c];
    double m = 0.0;
    float cnt = 0.0f;
    if (c < 3) a_next[apk_off(b * 20, n)] = 0;     // zero input at t=0
    for (int t = 0; t < CYCLES; ++t) {
        m = m + scr[(b_loc * 20 + t) * 33 + n_loc] + bv;
        bool sp = (th < m);
        if (sp) m -= th;
        if (c < 3) {
            if (t + 1 < CYCLES) a_next[apk_off(b * 20 + t + 1, n)] = sp ? 1 : 0;
        } else if (sp) {
            cnt += 1.0f;
        }
    }
    if (c == 3) out[(size_t)b * N_DIM + n] = cnt * 0.0625f;  // /16, exact
}

extern "C" void kernel_launch(void* const* d_in, const int* in_sizes, int n_in,
                              void* d_out, int out_size, void* d_ws, size_t ws_size,
                              hipStream_t stream) {
    const float* x       = (const float*)d_in[0];
    const float* wts     = (const float*)d_in[1];
    const float* biases  = (const float*)d_in[2];
    const float* thr     = (const float*)d_in[3];
    float* out           = (float*)d_out;

    signed char* wq  = (signed char*)d_ws;
    signed char* sig = (signed char*)((char*)d_ws + SIG_OFF);

    // prep0: pack W0 + build packed core-0 input spikes (no memsets needed:
    // every consumed byte is written by a producer before its consumer runs).
    prep0<<<dim3(3584), dim3(256), 0, stream>>>(wts, wq, x, sig);

    // 4 pipeline stages: fused GEMM+scan, with W_{c+1} pack overlapped.
    for (int c = 0; c < C_DIM; ++c) {
        const signed char* a_cur = sig + (size_t)c * AMAT_BYTES;
        signed char* a_nxt = (c < 3) ? (signed char*)(sig + (size_t)(c + 1) * AMAT_BYTES)
                                     : (signed char*)sig;   // unused for c==3
        int grid = (c < 3) ? 1536 : 512;
        gemm_core<<<dim3(grid), dim3(256), 0, stream>>>(wq, a_cur, wts, biases,
                                                        thr, a_nxt, out, c);
    }
}

// Round 13
// 107.238 us; speedup vs baseline: 1.2185x; 1.0517x over previous
//
#include <hip/hip_runtime.h>
#include <cstdint>
#include <cstddef>

// SpikingHybridCoreFlow: 20-cycle spiking simulation.
// Exactness strategy (unchanged): fixed-point weights (4 x i8 planes, scale
// 2^-33), i8 MFMA integer GEMM (order-independent exact), fp64 membrane.
//
// R13: exact revert to R6 (best measured: 107.4us). R7-R12 post-mortems:
// every structural variant regressed -- 3rd LDS buffer (R7: 55KB block, lost
// co-resident WG), VGPR cap (R8: acc demoted to 64 regs), counted-vmcnt asm
// (R10: defeats compiler scheduling), zero-sync streaming (R11: 2x L2
// traffic), 2-kstep buffers (R12: 73.7KB -> hard 2 WG/CU cap, and fewer
// barriers didn't help = barrier-drain theory falsified). R6's 42,240B block
// admits 3 WGs/CU backfill, compiler-scheduled 2-phase loop, 5/5/4/4 stage
// split: local optimum in all six perturbation directions.

#define N_DIM 2048
#define B_DIM 64
#define C_DIM 4
#define T_SIM 16
#define CYCLES 20
#define M_ROWS (CYCLES * B_DIM)          // 1280

using i32x4 = __attribute__((ext_vector_type(4))) int;
using u32x4 = __attribute__((ext_vector_type(4))) uint32_t;

// Workspace layout
//   WQ  : [C][128 strips][32 ksteps][4 planes][1024B] = 67,108,864 B
//   SIG : 4 x packed A matrices [80 mt][32 ks][1024B]  = 10,485,760 B
static constexpr size_t WQ_CORE    = (size_t)128 * 32 * 4 * 1024;   // 16 MB
static constexpr size_t SIG_OFF    = (size_t)C_DIM * WQ_CORE;
static constexpr size_t AMAT_BYTES = (size_t)M_ROWS * N_DIM;

// Packed-A byte offset for logical (m, k); m = b*20 + t.
//   block = (m>>4)*32 + (k>>6); in-block = ((k>>4)&3)*256 + (m&15)*16 + (k&15)
// = the i8 16x16x64 A-fragment order (lane*16 + j).
__device__ __forceinline__ size_t apk_off(int m, int k) {
    return ((size_t)((m >> 4) * 32 + (k >> 6)) << 10)
         + (size_t)((((k >> 4) & 3) << 8) + ((m & 15) << 4) + (k & 15));
}

// ---------------------------------------------------------------------------
// Pack one (ct,ks) block of one core's W: fp32 -> i32 fixed point (scale 2^33)
// -> 4 balanced i8 planes, MFMA B-fragment order, coalesced dwordx4 stores.
// ---------------------------------------------------------------------------
__device__ __forceinline__ void pack_unit(const float* __restrict__ wc,
                                          signed char* __restrict__ wqc,
                                          int unit, int l) {
    int ct = unit & 127;
    int ks = unit >> 7;                // 0..31
    int n     = ct * 16 + (l & 15);
    int abase = ks * 64 + ((l >> 4) << 4);
    size_t blk_base = (((size_t)ct * 32 + ks) * 4) * 1024 + (size_t)l * 16;

    u32x4 d0, d1, d2, d3;
    for (int j4 = 0; j4 < 4; ++j4) {
        uint32_t w0 = 0, w1 = 0, w2 = 0, w3 = 0;
        for (int i = 0; i < 4; ++i) {
            int a = abase + j4 * 4 + i;
            float wv = wc[(size_t)a * N_DIM + n];
            long long vi = llrintf(wv * 8589934592.0f);        // * 2^33, exact
            int v  = (int)vi;
            int b0 = (int)(signed char)(v & 255); v = (v - b0) >> 8;
            int b1 = (int)(signed char)(v & 255); v = (v - b1) >> 8;
            int b2 = (int)(signed char)(v & 255); v = (v - b2) >> 8;
            int b3 = v;
            w0 |= (uint32_t)(uint8_t)b0 << (8 * i);
            w1 |= (uint32_t)(uint8_t)b1 << (8 * i);
            w2 |= (uint32_t)(uint8_t)b2 << (8 * i);
            w3 |= (uint32_t)(uint8_t)b3 << (8 * i);
        }
        d0[j4] = w0; d1[j4] = w1; d2[j4] = w2; d3[j4] = w3;
    }
    *(u32x4*)(wqc + blk_base)        = d0;
    *(u32x4*)(wqc + blk_base + 1024) = d1;
    *(u32x4*)(wqc + blk_base + 2048) = d2;
    *(u32x4*)(wqc + blk_base + 3072) = d3;
}

// ---------------------------------------------------------------------------
// Bit-exact replication of _uniform_spikes (IEEE fp32, like XLA).
// ---------------------------------------------------------------------------
__device__ __forceinline__ int in_spike(float xv, int cycle) {
    if (cycle >= T_SIM) return 0;
    float n_spk = rintf(xv * 16.0f);
    if (n_spk == 16.0f) return 1;
    if (n_spk == 0.0f)  return 0;
    float spacing = 16.0f / n_spk;
    float cf = (float)cycle;
    float q = floorf(cf / spacing);
    float r = fmodf(cf, spacing);
    return (q < n_spk && floorf(r) == 0.0f) ? 1 : 0;
}

// Packed core-0 A element group: row m = b*20 + t, 4 n's per thread.
__device__ __forceinline__ void gen_unit(const float* __restrict__ x,
                                         signed char* __restrict__ a0, int gid) {
    int e   = gid << 2;                            // logical m*2048 + n byte idx
    int row = e >> 11;                             // m = b*20 + t
    int b = row / 20, t = row - b * 20;
    int n0 = e & 2047;
    const float4 xv = *(const float4*)(x + (size_t)b * N_DIM + n0);
    uint32_t s = (uint32_t)in_spike(xv.x, t)
               | ((uint32_t)in_spike(xv.y, t) << 8)
               | ((uint32_t)in_spike(xv.z, t) << 16)
               | ((uint32_t)in_spike(xv.w, t) << 24);
    *(uint32_t*)(a0 + apk_off(row, n0)) = s;
}

// prep0: blocks [0,1024) pack core-0 W (4 units each); [1024,3584) gen input.
__global__ __launch_bounds__(256) void prep0(const float* __restrict__ w,
                                             signed char* __restrict__ wq,
                                             const float* __restrict__ x,
                                             signed char* __restrict__ a0) {
    int wg = blockIdx.x, tid = threadIdx.x;
    if (wg < 1024) {
        pack_unit(w, wq, (wg << 2) | (tid >> 6), tid & 63);
    } else {
        gen_unit(x, a0, (wg - 1024) * 256 + tid);
    }
}

// ---------------------------------------------------------------------------
// Fused batched-GEMM + threshold-scan for one core, + overlapped W_{c+1} pack.
// Gemm WGs (wg<512): 8 m-eighths (8 b's = 160 rows = 10 m-tiles) x 64 strips
// (32 cols). 256 thr = 4 waves; wave wv: nc = wv&1, m-tiles (wv>>1)*5+0..4
// -> acc[5][4] (80 VGPR). Per kstep stage 18KB (10 A + 8 B blocks) into
// lds[buf^1] before computing lds[buf] (20 MFMAs/wave); one __syncthreads
// per kstep. 42,240B block -> up to 3 WGs/CU; cross-WG overlap hides drain.
// Epilogue: exact plane combine -> fp64 scr[160][33] -> per-(b,n) 20-step
// threshold scan -> packed spikes for next core / output.
// Pack WGs (wg>=512, c<3): pack W_{c+1} (memory-bound, overlaps gemm).
// ---------------------------------------------------------------------------
__global__ __launch_bounds__(256, 2) void gemm_core(
        signed char* __restrict__ wq, const signed char* __restrict__ apk,
        const float* __restrict__ wts, const float* __restrict__ biases,
        const float* __restrict__ thresholds,
        signed char* __restrict__ a_next, float* __restrict__ out, int c)
{
    __shared__ __align__(16) signed char smem[42240];   // 2x18KB stage / scr
    const int wg  = blockIdx.x;
    const int tid = threadIdx.x;
    const int wv  = tid >> 6;          // 0..3
    const int l   = tid & 63;

    if (wg >= 512) {                   // overlapped pack of W_{c+1}
        pack_unit(wts + (size_t)(c + 1) * N_DIM * N_DIM,
                  wq + (size_t)(c + 1) * WQ_CORE,
                  ((wg - 512) << 2) | wv, l);
        return;
    }

    const int e8 = wg >> 6;            // m-eighth: b in [8*e8, 8*e8+8)
    const int s  = wg & 63;            // 32-col strip: n in [32s, 32s+32)

    const signed char* asrc  = apk + ((size_t)(e8 * 10) * 32) * 1024;
    const signed char* b0src = wq + ((size_t)(c * 128 + s * 2) * 32) * 4096;
    const signed char* b1src = wq + ((size_t)(c * 128 + s * 2 + 1) * 32) * 4096;

    // Stage slice ks into buffer buf. Waves 0,1: A blocks (5 each);
    // waves 2,3: B strip0/strip1 (4 plane-blocks each). 1KB per DMA load.
    auto STAGE = [&](int buf, int ks) {
        signed char* dst = smem + buf * 18432;
        if (wv < 2) {
#pragma unroll
            for (int r = 0; r < 5; ++r) {
                int blk = wv * 5 + r;
                __builtin_amdgcn_global_load_lds(
                    (const __attribute__((address_space(1))) uint32_t*)
                        (asrc + ((size_t)blk * 32 + ks) * 1024 + l * 16),
                    (__attribute__((address_space(3))) uint32_t*)(dst + blk * 1024),
                    16, 0, 0);
            }
        } else {
            const signed char* bs = (wv == 2) ? b0src : b1src;
#pragma unroll
            for (int p = 0; p < 4; ++p) {
                __builtin_amdgcn_global_load_lds(
                    (const __attribute__((address_space(1))) uint32_t*)
                        (bs + (size_t)ks * 4096 + p * 1024 + l * 16),
                    (__attribute__((address_space(3))) uint32_t*)
                        (dst + 10240 + (wv - 2) * 4096 + p * 1024),
                    16, 0, 0);
            }
        }
    };

    const int nc  = wv & 1;            // n-fragment (16 cols)
    const int mtb = (wv >> 1) * 5;     // first of 5 m-tiles

    i32x4 acc[5][4];
#pragma unroll
    for (int j = 0; j < 5; ++j)
#pragma unroll
        for (int p = 0; p < 4; ++p) acc[j][p] = i32x4{0, 0, 0, 0};

    STAGE(0, 0);
    __syncthreads();
    int cur = 0;

    for (int ks = 0; ks < 32; ++ks) {
        if (ks < 31) STAGE(cur ^ 1, ks + 1);
        const signed char* lb = smem + cur * 18432 + (size_t)l * 16;
        i32x4 bf0 = *(const i32x4*)(lb + 10240 + nc * 4096);
        i32x4 bf1 = *(const i32x4*)(lb + 10240 + nc * 4096 + 1024);
        i32x4 bf2 = *(const i32x4*)(lb + 10240 + nc * 4096 + 2048);
        i32x4 bf3 = *(const i32x4*)(lb + 10240 + nc * 4096 + 3072);
#pragma unroll
        for (int j = 0; j < 5; ++j) {
            i32x4 af = *(const i32x4*)(lb + (mtb + j) * 1024);
            acc[j][0] = __builtin_amdgcn_mfma_i32_16x16x64_i8(af, bf0, acc[j][0], 0, 0, 0);
            acc[j][1] = __builtin_amdgcn_mfma_i32_16x16x64_i8(af, bf1, acc[j][1], 0, 0, 0);
            acc[j][2] = __builtin_amdgcn_mfma_i32_16x16x64_i8(af, bf2, acc[j][2], 0, 0, 0);
            acc[j][3] = __builtin_amdgcn_mfma_i32_16x16x64_i8(af, bf3, acc[j][3], 0, 0, 0);
        }
        __syncthreads();
        cur ^= 1;
    }

    // ---- Fused epilogue ----
    // 1. Combine planes exactly -> fp64 increments into LDS (staging is dead).
    double* scr = (double*)smem;       // [160][33]
    const int nl = nc * 16 + (l & 15);
#pragma unroll
    for (int j = 0; j < 5; ++j) {
#pragma unroll
        for (int r = 0; r < 4; ++r) {
            int rl = (mtb + j) * 16 + ((l >> 4) << 2) + r;   // local row 0..159
            long long comb = ((long long)acc[j][3][r] << 24) + ((long long)acc[j][2][r] << 16)
                           + ((long long)acc[j][1][r] << 8)  +  (long long)acc[j][0][r];
            scr[rl * 33 + nl] = (double)comb * (1.0 / 8589934592.0);
        }
    }
    __syncthreads();

    // 2. Per-(b,n) threshold scan over t=0..19; thread <-> (b_loc, n_loc).
    const int b_loc = tid >> 5;        // 0..7
    const int n_loc = tid & 31;        // 0..31
    const int b = e8 * 8 + b_loc;
    const int n = (s << 5) + n_loc;
    const double bv = (double)biases[c * N_DIM + n];
    const double th = (double)thresholds[c];
    double m = 0.0;
    float cnt = 0.0f;
    if (c < 3) a_next[apk_off(b * 20, n)] = 0;     // zero input at t=0
    for (int t = 0; t < CYCLES; ++t) {
        m = m + scr[(b_loc * 20 + t) * 33 + n_loc] + bv;
        bool sp = (th < m);
        if (sp) m -= th;
        if (c < 3) {
            if (t + 1 < CYCLES) a_next[apk_off(b * 20 + t + 1, n)] = sp ? 1 : 0;
        } else if (sp) {
            cnt += 1.0f;
        }
    }
    if (c == 3) out[(size_t)b * N_DIM + n] = cnt * 0.0625f;  // /16, exact
}

extern "C" void kernel_launch(void* const* d_in, const int* in_sizes, int n_in,
                              void* d_out, int out_size, void* d_ws, size_t ws_size,
                              hipStream_t stream) {
    const float* x       = (const float*)d_in[0];
    const float* wts     = (const float*)d_in[1];
    const float* biases  = (const float*)d_in[2];
    const float* thr     = (const float*)d_in[3];
    float* out           = (float*)d_out;

    signed char* wq  = (signed char*)d_ws;
    signed char* sig = (signed char*)((char*)d_ws + SIG_OFF);

    // prep0: pack W0 + build packed core-0 input spikes (no memsets needed:
    // every consumed byte is written by a producer before its consumer runs).
    prep0<<<dim3(3584), dim3(256), 0, stream>>>(wts, wq, x, sig);

    // 4 pipeline stages: fused GEMM+scan, with W_{c+1} pack overlapped.
    for (int c = 0; c < C_DIM; ++c) {
        const signed char* a_cur = sig + (size_t)c * AMAT_BYTES;
        signed char* a_nxt = (c < 3) ? (signed char*)(sig + (size_t)(c + 1) * AMAT_BYTES)
                                     : (signed char*)sig;   // unused for c==3
        int grid = (c < 3) ? 1536 : 512;
        gemm_core<<<dim3(grid), dim3(256), 0, stream>>>(wq, a_cur, wts, biases,
                                                        thr, a_nxt, out, c);
    }
}

// Round 14
// 104.374 us; speedup vs baseline: 1.2520x; 1.0274x over previous
//
#include <hip/hip_runtime.h>
#include <cstdint>
#include <cstddef>

// SpikingHybridCoreFlow: 20-cycle spiking simulation.
// Exactness strategy (unchanged): fixed-point weights (4 x i8 planes, scale
// 2^-33), i8 MFMA integer GEMM (order-independent exact), fp64 membrane.
//
// R14: R13 (= R6, best measured 107.2us, reproduced) + T5 s_setprio around
// the MFMA cluster. Rationale: CUs host gemm waves AND pack waves (memory
// streamers) -> genuine role diversity, the stated prerequisite for setprio
// (m191); m190's GEMM-null was lockstep-only. Zero-risk hint: no footprint,
// no asm waits, no reg-cap (R7-R12 failure modes absent).

#define N_DIM 2048
#define B_DIM 64
#define C_DIM 4
#define T_SIM 16
#define CYCLES 20
#define M_ROWS (CYCLES * B_DIM)          // 1280

using i32x4 = __attribute__((ext_vector_type(4))) int;
using u32x4 = __attribute__((ext_vector_type(4))) uint32_t;

// Workspace layout
//   WQ  : [C][128 strips][32 ksteps][4 planes][1024B] = 67,108,864 B
//   SIG : 4 x packed A matrices [80 mt][32 ks][1024B]  = 10,485,760 B
static constexpr size_t WQ_CORE    = (size_t)128 * 32 * 4 * 1024;   // 16 MB
static constexpr size_t SIG_OFF    = (size_t)C_DIM * WQ_CORE;
static constexpr size_t AMAT_BYTES = (size_t)M_ROWS * N_DIM;

// Packed-A byte offset for logical (m, k); m = b*20 + t.
//   block = (m>>4)*32 + (k>>6); in-block = ((k>>4)&3)*256 + (m&15)*16 + (k&15)
// = the i8 16x16x64 A-fragment order (lane*16 + j).
__device__ __forceinline__ size_t apk_off(int m, int k) {
    return ((size_t)((m >> 4) * 32 + (k >> 6)) << 10)
         + (size_t)((((k >> 4) & 3) << 8) + ((m & 15) << 4) + (k & 15));
}

// ---------------------------------------------------------------------------
// Pack one (ct,ks) block of one core's W: fp32 -> i32 fixed point (scale 2^33)
// -> 4 balanced i8 planes, MFMA B-fragment order, coalesced dwordx4 stores.
// ---------------------------------------------------------------------------
__device__ __forceinline__ void pack_unit(const float* __restrict__ wc,
                                          signed char* __restrict__ wqc,
                                          int unit, int l) {
    int ct = unit & 127;
    int ks = unit >> 7;                // 0..31
    int n     = ct * 16 + (l & 15);
    int abase = ks * 64 + ((l >> 4) << 4);
    size_t blk_base = (((size_t)ct * 32 + ks) * 4) * 1024 + (size_t)l * 16;

    u32x4 d0, d1, d2, d3;
    for (int j4 = 0; j4 < 4; ++j4) {
        uint32_t w0 = 0, w1 = 0, w2 = 0, w3 = 0;
        for (int i = 0; i < 4; ++i) {
            int a = abase + j4 * 4 + i;
            float wv = wc[(size_t)a * N_DIM + n];
            long long vi = llrintf(wv * 8589934592.0f);        // * 2^33, exact
            int v  = (int)vi;
            int b0 = (int)(signed char)(v & 255); v = (v - b0) >> 8;
            int b1 = (int)(signed char)(v & 255); v = (v - b1) >> 8;
            int b2 = (int)(signed char)(v & 255); v = (v - b2) >> 8;
            int b3 = v;
            w0 |= (uint32_t)(uint8_t)b0 << (8 * i);
            w1 |= (uint32_t)(uint8_t)b1 << (8 * i);
            w2 |= (uint32_t)(uint8_t)b2 << (8 * i);
            w3 |= (uint32_t)(uint8_t)b3 << (8 * i);
        }
        d0[j4] = w0; d1[j4] = w1; d2[j4] = w2; d3[j4] = w3;
    }
    *(u32x4*)(wqc + blk_base)        = d0;
    *(u32x4*)(wqc + blk_base + 1024) = d1;
    *(u32x4*)(wqc + blk_base + 2048) = d2;
    *(u32x4*)(wqc + blk_base + 3072) = d3;
}

// ---------------------------------------------------------------------------
// Bit-exact replication of _uniform_spikes (IEEE fp32, like XLA).
// ---------------------------------------------------------------------------
__device__ __forceinline__ int in_spike(float xv, int cycle) {
    if (cycle >= T_SIM) return 0;
    float n_spk = rintf(xv * 16.0f);
    if (n_spk == 16.0f) return 1;
    if (n_spk == 0.0f)  return 0;
    float spacing = 16.0f / n_spk;
    float cf = (float)cycle;
    float q = floorf(cf / spacing);
    float r = fmodf(cf, spacing);
    return (q < n_spk && floorf(r) == 0.0f) ? 1 : 0;
}

// Packed core-0 A element group: row m = b*20 + t, 4 n's per thread.
__device__ __forceinline__ void gen_unit(const float* __restrict__ x,
                                         signed char* __restrict__ a0, int gid) {
    int e   = gid << 2;                            // logical m*2048 + n byte idx
    int row = e >> 11;                             // m = b*20 + t
    int b = row / 20, t = row - b * 20;
    int n0 = e & 2047;
    const float4 xv = *(const float4*)(x + (size_t)b * N_DIM + n0);
    uint32_t s = (uint32_t)in_spike(xv.x, t)
               | ((uint32_t)in_spike(xv.y, t) << 8)
               | ((uint32_t)in_spike(xv.z, t) << 16)
               | ((uint32_t)in_spike(xv.w, t) << 24);
    *(uint32_t*)(a0 + apk_off(row, n0)) = s;
}

// prep0: blocks [0,1024) pack core-0 W (4 units each); [1024,3584) gen input.
__global__ __launch_bounds__(256) void prep0(const float* __restrict__ w,
                                             signed char* __restrict__ wq,
                                             const float* __restrict__ x,
                                             signed char* __restrict__ a0) {
    int wg = blockIdx.x, tid = threadIdx.x;
    if (wg < 1024) {
        pack_unit(w, wq, (wg << 2) | (tid >> 6), tid & 63);
    } else {
        gen_unit(x, a0, (wg - 1024) * 256 + tid);
    }
}

// ---------------------------------------------------------------------------
// Fused batched-GEMM + threshold-scan for one core, + overlapped W_{c+1} pack.
// Gemm WGs (wg<512): 8 m-eighths (8 b's = 160 rows = 10 m-tiles) x 64 strips
// (32 cols). 256 thr = 4 waves; wave wv: nc = wv&1, m-tiles (wv>>1)*5+0..4
// -> acc[5][4] (80 VGPR). Per kstep stage 18KB (10 A + 8 B blocks) into
// lds[buf^1] before computing lds[buf] (20 MFMAs/wave, setprio-wrapped);
// one __syncthreads per kstep. 42,240B block -> up to 3 WGs/CU.
// Epilogue: exact plane combine -> fp64 scr[160][33] -> per-(b,n) 20-step
// threshold scan -> packed spikes for next core / output.
// Pack WGs (wg>=512, c<3): pack W_{c+1} (memory-bound, overlaps gemm).
// ---------------------------------------------------------------------------
__global__ __launch_bounds__(256, 2) void gemm_core(
        signed char* __restrict__ wq, const signed char* __restrict__ apk,
        const float* __restrict__ wts, const float* __restrict__ biases,
        const float* __restrict__ thresholds,
        signed char* __restrict__ a_next, float* __restrict__ out, int c)
{
    __shared__ __align__(16) signed char smem[42240];   // 2x18KB stage / scr
    const int wg  = blockIdx.x;
    const int tid = threadIdx.x;
    const int wv  = tid >> 6;          // 0..3
    const int l   = tid & 63;

    if (wg >= 512) {                   // overlapped pack of W_{c+1}
        pack_unit(wts + (size_t)(c + 1) * N_DIM * N_DIM,
                  wq + (size_t)(c + 1) * WQ_CORE,
                  ((wg - 512) << 2) | wv, l);
        return;
    }

    const int e8 = wg >> 6;            // m-eighth: b in [8*e8, 8*e8+8)
    const int s  = wg & 63;            // 32-col strip: n in [32s, 32s+32)

    const signed char* asrc  = apk + ((size_t)(e8 * 10) * 32) * 1024;
    const signed char* b0src = wq + ((size_t)(c * 128 + s * 2) * 32) * 4096;
    const signed char* b1src = wq + ((size_t)(c * 128 + s * 2 + 1) * 32) * 4096;

    // Stage slice ks into buffer buf. Waves 0,1: A blocks (5 each);
    // waves 2,3: B strip0/strip1 (4 plane-blocks each). 1KB per DMA load.
    auto STAGE = [&](int buf, int ks) {
        signed char* dst = smem + buf * 18432;
        if (wv < 2) {
#pragma unroll
            for (int r = 0; r < 5; ++r) {
                int blk = wv * 5 + r;
                __builtin_amdgcn_global_load_lds(
                    (const __attribute__((address_space(1))) uint32_t*)
                        (asrc + ((size_t)blk * 32 + ks) * 1024 + l * 16),
                    (__attribute__((address_space(3))) uint32_t*)(dst + blk * 1024),
                    16, 0, 0);
            }
        } else {
            const signed char* bs = (wv == 2) ? b0src : b1src;
#pragma unroll
            for (int p = 0; p < 4; ++p) {
                __builtin_amdgcn_global_load_lds(
                    (const __attribute__((address_space(1))) uint32_t*)
                        (bs + (size_t)ks * 4096 + p * 1024 + l * 16),
                    (__attribute__((address_space(3))) uint32_t*)
                        (dst + 10240 + (wv - 2) * 4096 + p * 1024),
                    16, 0, 0);
            }
        }
    };

    const int nc  = wv & 1;            // n-fragment (16 cols)
    const int mtb = (wv >> 1) * 5;     // first of 5 m-tiles

    i32x4 acc[5][4];
#pragma unroll
    for (int j = 0; j < 5; ++j)
#pragma unroll
        for (int p = 0; p < 4; ++p) acc[j][p] = i32x4{0, 0, 0, 0};

    STAGE(0, 0);
    __syncthreads();
    int cur = 0;

    for (int ks = 0; ks < 32; ++ks) {
        if (ks < 31) STAGE(cur ^ 1, ks + 1);
        const signed char* lb = smem + cur * 18432 + (size_t)l * 16;
        i32x4 bf0 = *(const i32x4*)(lb + 10240 + nc * 4096);
        i32x4 bf1 = *(const i32x4*)(lb + 10240 + nc * 4096 + 1024);
        i32x4 bf2 = *(const i32x4*)(lb + 10240 + nc * 4096 + 2048);
        i32x4 bf3 = *(const i32x4*)(lb + 10240 + nc * 4096 + 3072);
        __builtin_amdgcn_s_setprio(1);             // T5: favor MFMA cluster
#pragma unroll
        for (int j = 0; j < 5; ++j) {
            i32x4 af = *(const i32x4*)(lb + (mtb + j) * 1024);
            acc[j][0] = __builtin_amdgcn_mfma_i32_16x16x64_i8(af, bf0, acc[j][0], 0, 0, 0);
            acc[j][1] = __builtin_amdgcn_mfma_i32_16x16x64_i8(af, bf1, acc[j][1], 0, 0, 0);
            acc[j][2] = __builtin_amdgcn_mfma_i32_16x16x64_i8(af, bf2, acc[j][2], 0, 0, 0);
            acc[j][3] = __builtin_amdgcn_mfma_i32_16x16x64_i8(af, bf3, acc[j][3], 0, 0, 0);
        }
        __builtin_amdgcn_s_setprio(0);
        __syncthreads();
        cur ^= 1;
    }

    // ---- Fused epilogue ----
    // 1. Combine planes exactly -> fp64 increments into LDS (staging is dead).
    double* scr = (double*)smem;       // [160][33]
    const int nl = nc * 16 + (l & 15);
#pragma unroll
    for (int j = 0; j < 5; ++j) {
#pragma unroll
        for (int r = 0; r < 4; ++r) {
            int rl = (mtb + j) * 16 + ((l >> 4) << 2) + r;   // local row 0..159
            long long comb = ((long long)acc[j][3][r] << 24) + ((long long)acc[j][2][r] << 16)
                           + ((long long)acc[j][1][r] << 8)  +  (long long)acc[j][0][r];
            scr[rl * 33 + nl] = (double)comb * (1.0 / 8589934592.0);
        }
    }
    __syncthreads();

    // 2. Per-(b,n) threshold scan over t=0..19; thread <-> (b_loc, n_loc).
    const int b_loc = tid >> 5;        // 0..7
    const int n_loc = tid & 31;        // 0..31
    const int b = e8 * 8 + b_loc;
    const int n = (s << 5) + n_loc;
    const double bv = (double)biases[c * N_DIM + n];
    const double th = (double)thresholds[c];
    double m = 0.0;
    float cnt = 0.0f;
    if (c < 3) a_next[apk_off(b * 20, n)] = 0;     // zero input at t=0
    for (int t = 0; t < CYCLES; ++t) {
        m = m + scr[(b_loc * 20 + t) * 33 + n_loc] + bv;
        bool sp = (th < m);
        if (sp) m -= th;
        if (c < 3) {
            if (t + 1 < CYCLES) a_next[apk_off(b * 20 + t + 1, n)] = sp ? 1 : 0;
        } else if (sp) {
            cnt += 1.0f;
        }
    }
    if (c == 3) out[(size_t)b * N_DIM + n] = cnt * 0.0625f;  // /16, exact
}

extern "C" void kernel_launch(void* const* d_in, const int* in_sizes, int n_in,
                              void* d_out, int out_size, void* d_ws, size_t ws_size,
                              hipStream_t stream) {
    const float* x       = (const float*)d_in[0];
    const float* wts     = (const float*)d_in[1];
    const float* biases  = (const float*)d_in[2];
    const float* thr     = (const float*)d_in[3];
    float* out           = (float*)d_out;

    signed char* wq  = (signed char*)d_ws;
    signed char* sig = (signed char*)((char*)d_ws + SIG_OFF);

    // prep0: pack W0 + build packed core-0 input spikes (no memsets needed:
    // every consumed byte is written by a producer before its consumer runs).
    prep0<<<dim3(3584), dim3(256), 0, stream>>>(wts, wq, x, sig);

    // 4 pipeline stages: fused GEMM+scan, with W_{c+1} pack overlapped.
    for (int c = 0; c < C_DIM; ++c) {
        const signed char* a_cur = sig + (size_t)c * AMAT_BYTES;
        signed char* a_nxt = (c < 3) ? (signed char*)(sig + (size_t)(c + 1) * AMAT_BYTES)
                                     : (signed char*)sig;   // unused for c==3
        int grid = (c < 3) ? 1536 : 512;
        gemm_core<<<dim3(grid), dim3(256), 0, stream>>>(wq, a_cur, wts, biases,
                                                        thr, a_nxt, out, c);
    }
}